// Round 1
// baseline (514.219 us; speedup 1.0000x reference)
//
#include <hip/hip_runtime.h>
#include <math.h>

#define N_NODES 50000
#define N_EDGES 800000
#define NGRAPH  1024
#define IN_DIM  25
#define DIM     64

__device__ inline float wsum(float v) {
#pragma unroll
  for (int off = 32; off > 0; off >>= 1) v += __shfl_xor(v, off, 64);
  return v;
}
__device__ inline float sigmoidf(float x) { return 1.f / (1.f + expf(-x)); }

// ---------------- lin0 + relu + @Wc fused ----------------
__global__ __launch_bounds__(256) void k_lin0(const float* __restrict__ x,
    const float* __restrict__ W0, const float* __restrict__ b0,
    const float* __restrict__ Wc, float* __restrict__ hw) {
  __shared__ float sW0[IN_DIM * DIM];
  __shared__ float sWc[DIM * DIM];
  __shared__ float sb0[DIM];
  __shared__ float sx[4][IN_DIM];
  __shared__ float sh0[4][DIM];
  int t = threadIdx.x;
  for (int i = t; i < IN_DIM * DIM; i += 256) sW0[i] = W0[i];
  for (int i = t; i < DIM * DIM; i += 256) sWc[i] = Wc[i];
  if (t < DIM) sb0[t] = b0[t];
  __syncthreads();
  int sub = t >> 6, lane = t & 63;
  const int ITER = 16;
  int base = blockIdx.x * (4 * ITER);
  for (int r = 0; r < ITER; r++) {
    int row = base + r * 4 + sub;
    if (row < N_NODES && lane < IN_DIM) sx[sub][lane] = x[row * IN_DIM + lane];
    __syncthreads();
    float acc = sb0[lane];
#pragma unroll
    for (int k = 0; k < IN_DIM; k++) acc += sx[sub][k] * sW0[k * DIM + lane];
    acc = fmaxf(acc, 0.f);
    sh0[sub][lane] = acc;
    __syncthreads();
    float o = 0.f;
#pragma unroll
    for (int k = 0; k < DIM; k++) o += sh0[sub][k] * sWc[k * DIM + lane];
    if (row < N_NODES) hw[row * DIM + lane] = o;
    __syncthreads();
  }
}

// ---------------- degree ----------------
__global__ void k_deg_init(float* deg) {
  int i = blockIdx.x * blockDim.x + threadIdx.x;
  if (i < N_NODES) deg[i] = 1.0f;  // self loop
}
__global__ void k_degc(const int* __restrict__ ei, float* deg) {
  int e = blockIdx.x * blockDim.x + threadIdx.x;
  if (e < N_EDGES) atomicAdd(&deg[ei[N_EDGES + e]], 1.0f);
}
__global__ void k_dinv(float* deg) {
  int i = blockIdx.x * blockDim.x + threadIdx.x;
  if (i < N_NODES) deg[i] = rsqrtf(deg[i]);  // deg >= 1 always
}

// ---------------- GCN aggregate ----------------
__global__ void k_agg_init(const float* __restrict__ hw,
                           const float* __restrict__ dinv, float* __restrict__ agg) {
  int i = blockIdx.x * blockDim.x + threadIdx.x;
  if (i < N_NODES * DIM) {
    int row = i >> 6;
    float di = dinv[row];
    agg[i] = hw[i] * di * di;  // self-loop message
  }
}
__global__ __launch_bounds__(256) void k_scatter(const int* __restrict__ ei,
    const float* __restrict__ hw, const float* __restrict__ dinv,
    float* __restrict__ agg) {
  int e = blockIdx.x * 4 + (threadIdx.x >> 6);
  int lane = threadIdx.x & 63;
  if (e >= N_EDGES) return;
  int row = ei[e];
  int col = ei[N_EDGES + e];
  float norm = dinv[row] * dinv[col];
  float v = hw[row * DIM + lane] * norm;
  atomicAdd(&agg[col * DIM + lane], v);
}
__global__ void k_relu_bc(float* __restrict__ h, const float* __restrict__ bc) {
  int i = blockIdx.x * blockDim.x + threadIdx.x;
  if (i < N_NODES * DIM) h[i] = fmaxf(h[i] + bc[i & 63], 0.f);
}

// ---------------- graph boundaries (batch is sorted) ----------------
__global__ void k_starts(const int* __restrict__ batch, int* __restrict__ start) {
  int g = blockIdx.x * blockDim.x + threadIdx.x;
  if (g > NGRAPH) return;
  if (g == NGRAPH) { start[NGRAPH] = N_NODES; return; }
  int lo = 0, hi = N_NODES;
  while (lo < hi) {
    int mid = (lo + hi) >> 1;
    if (batch[mid] < g) lo = mid + 1; else hi = mid;
  }
  start[g] = lo;
}

__global__ void k_zero(float* p, int n) {
  int i = blockIdx.x * blockDim.x + threadIdx.x;
  if (i < n) p[i] = 0.f;
}

// ---------------- LSTM cell (one block per graph) ----------------
__global__ __launch_bounds__(256) void k_lstm(const float* __restrict__ Wih,
    const float* __restrict__ Whh, const float* __restrict__ bih,
    const float* __restrict__ bhh, float* __restrict__ hs, float* __restrict__ cs,
    float* __restrict__ q_star) {
  int b = blockIdx.x, t = threadIdx.x;
  __shared__ float sq[2 * DIM];
  __shared__ float shh[DIM];
  __shared__ float gates[4 * DIM];
  if (t < 2 * DIM) sq[t] = q_star[b * 2 * DIM + t];
  else if (t < 3 * DIM) shh[t - 2 * DIM] = hs[b * DIM + (t - 2 * DIM)];
  __syncthreads();
  float g = bih[t] + bhh[t];
  const float* wr = Wih + t * 2 * DIM;
#pragma unroll 8
  for (int k = 0; k < 2 * DIM; k++) g += sq[k] * wr[k];
  const float* wh = Whh + t * DIM;
#pragma unroll 8
  for (int k = 0; k < DIM; k++) g += shh[k] * wh[k];
  gates[t] = g;
  __syncthreads();
  if (t < DIM) {
    float ig = sigmoidf(gates[t]);
    float fg = sigmoidf(gates[DIM + t]);
    float gg = tanhf(gates[2 * DIM + t]);
    float og = sigmoidf(gates[3 * DIM + t]);
    float c = fg * cs[b * DIM + t] + ig * gg;
    cs[b * DIM + t] = c;
    float hh = og * tanhf(c);
    hs[b * DIM + t] = hh;
    q_star[b * 2 * DIM + t] = hh;  // q half of q_star
  }
}

// ---------------- segment softmax attention (one block per graph) ----------------
#define MAXC 128
__global__ __launch_bounds__(256) void k_attn(const float* __restrict__ h,
    const float* __restrict__ hs, const int* __restrict__ start,
    float* __restrict__ q_star) {
  int b = blockIdx.x, t = threadIdx.x;
  int wave = t >> 6, lane = t & 63;
  __shared__ float sq[DIM];
  __shared__ float e_s[MAXC];
  __shared__ float red[4 * DIM];
  __shared__ float lred[4];
  int s = start[b], eend = start[b + 1];
  if (t < DIM) sq[t] = hs[b * DIM + t];
  __syncthreads();
  float m_run = -INFINITY, l_run = 0.f, racc = 0.f;
  for (int cb = s; cb < eend; cb += MAXC) {
    int cn = min(MAXC, eend - cb);
    for (int j = wave; j < cn; j += 4) {
      float p = h[(cb + j) * DIM + lane] * sq[lane];
      p = wsum(p);
      if (lane == 0) e_s[j] = p;
    }
    __syncthreads();
    float m_c = -INFINITY;
    for (int j = 0; j < cn; j++) m_c = fmaxf(m_c, e_s[j]);
    float m_new = fmaxf(m_run, m_c);
    float scale = expf(m_run - m_new);  // first chunk: exp(-inf)=0, racc/l are 0 anyway
    racc *= scale;
    l_run *= scale;
    m_run = m_new;
    for (int j = wave; j < cn; j += 4) {
      float a = expf(e_s[j] - m_run);
      l_run += a;  // lane-uniform within wave
      racc += a * h[(cb + j) * DIM + lane];
    }
    __syncthreads();
  }
  red[wave * DIM + lane] = racc;
  if (lane == 0) lred[wave] = l_run;
  __syncthreads();
  if (t < DIM) {
    float r = red[t] + red[DIM + t] + red[2 * DIM + t] + red[3 * DIM + t];
    float l = lred[0] + lred[1] + lred[2] + lred[3];
    r = (l > 0.f) ? r / l : 0.f;
    q_star[b * 2 * DIM + DIM + t] = r;
  }
}

// ---------------- output MLP (one wave per graph) ----------------
__global__ __launch_bounds__(64) void k_final(const float* __restrict__ q_star,
    const float* __restrict__ W1, const float* __restrict__ b1,
    const float* __restrict__ W2, const float* __restrict__ b2,
    float* __restrict__ out) {
  int b = blockIdx.x, t = threadIdx.x;
  __shared__ float sq[2 * DIM];
  sq[t] = q_star[b * 2 * DIM + t];
  sq[t + DIM] = q_star[b * 2 * DIM + DIM + t];
  __syncthreads();
  float acc = b1[t];
#pragma unroll 8
  for (int k = 0; k < 2 * DIM; k++) acc += sq[k] * W1[k * DIM + t];
  acc = fmaxf(acc, 0.f);
  float v = wsum(acc * W2[t]);
  if (t == 0) out[b] = v + b2[0];
}

extern "C" void kernel_launch(void* const* d_in, const int* in_sizes, int n_in,
                              void* d_out, int out_size, void* d_ws, size_t ws_size,
                              hipStream_t stream) {
  const float* x    = (const float*)d_in[0];
  const int*   ei   = (const int*)d_in[1];
  const int*   batch= (const int*)d_in[2];
  const float* W0   = (const float*)d_in[3];
  const float* b0   = (const float*)d_in[4];
  const float* Wc   = (const float*)d_in[5];
  const float* bc   = (const float*)d_in[6];
  const float* Wih  = (const float*)d_in[7];
  const float* Whh  = (const float*)d_in[8];
  const float* bih  = (const float*)d_in[9];
  const float* bhh  = (const float*)d_in[10];
  const float* W1   = (const float*)d_in[11];
  const float* b1   = (const float*)d_in[12];
  const float* W2   = (const float*)d_in[13];
  const float* b2   = (const float*)d_in[14];
  float* out = (float*)d_out;

  float* ws  = (float*)d_ws;
  float* hw  = ws;                         // N*DIM = 3,200,000 floats
  float* agg = ws + (size_t)N_NODES * DIM; // N*DIM (becomes h after relu)
  float* deg = agg + (size_t)N_NODES * DIM; // N floats (becomes dinv in place)
  float* hs  = deg + 60000;                // NGRAPH*DIM
  float* cs  = hs + NGRAPH * DIM;          // NGRAPH*DIM
  float* qst = cs + NGRAPH * DIM;          // NGRAPH*2*DIM
  int* start = (int*)(qst + NGRAPH * 2 * DIM);  // NGRAPH+1 ints

  k_lin0<<<(N_NODES + 63) / 64, 256, 0, stream>>>(x, W0, b0, Wc, hw);
  k_deg_init<<<(N_NODES + 255) / 256, 256, 0, stream>>>(deg);
  k_degc<<<(N_EDGES + 255) / 256, 256, 0, stream>>>(ei, deg);
  k_dinv<<<(N_NODES + 255) / 256, 256, 0, stream>>>(deg);
  k_agg_init<<<(N_NODES * DIM + 255) / 256, 256, 0, stream>>>(hw, deg, agg);
  k_scatter<<<(N_EDGES + 3) / 4, 256, 0, stream>>>(ei, hw, deg, agg);
  k_relu_bc<<<(N_NODES * DIM + 255) / 256, 256, 0, stream>>>(agg, bc);
  k_starts<<<(NGRAPH + 256) / 256, 256, 0, stream>>>(batch, start);
  k_zero<<<(NGRAPH * 4 * DIM + 255) / 256, 256, 0, stream>>>(hs, NGRAPH * 4 * DIM);
  for (int s = 0; s < 3; s++) {
    k_lstm<<<NGRAPH, 256, 0, stream>>>(Wih, Whh, bih, bhh, hs, cs, qst);
    k_attn<<<NGRAPH, 256, 0, stream>>>(agg, hs, start, qst);
  }
  k_final<<<NGRAPH, 64, 0, stream>>>(qst, W1, b1, W2, b2, out);
}

// Round 2
// 416.527 us; speedup vs baseline: 1.2345x; 1.2345x over previous
//
#include <hip/hip_runtime.h>
#include <math.h>

#define N_NODES 50000
#define N_EDGES 800000
#define NGRAPH  1024
#define IN_DIM  25
#define DIM     64

__device__ inline float wsum(float v) {
#pragma unroll
  for (int off = 32; off > 0; off >>= 1) v += __shfl_xor(v, off, 64);
  return v;
}
__device__ inline float sigmoidf(float x) { return 1.f / (1.f + expf(-x)); }

// ---------------- lin0 + relu + @Wc fused ----------------
__global__ __launch_bounds__(256) void k_lin0(const float* __restrict__ x,
    const float* __restrict__ W0, const float* __restrict__ b0,
    const float* __restrict__ Wc, float* __restrict__ hw) {
  __shared__ float sW0[IN_DIM * DIM];
  __shared__ float sWc[DIM * DIM];
  __shared__ float sb0[DIM];
  __shared__ float sx[4][IN_DIM];
  __shared__ float sh0[4][DIM];
  int t = threadIdx.x;
  for (int i = t; i < IN_DIM * DIM; i += 256) sW0[i] = W0[i];
  for (int i = t; i < DIM * DIM; i += 256) sWc[i] = Wc[i];
  if (t < DIM) sb0[t] = b0[t];
  __syncthreads();
  int sub = t >> 6, lane = t & 63;
  const int ITER = 16;
  int base = blockIdx.x * (4 * ITER);
  for (int r = 0; r < ITER; r++) {
    int row = base + r * 4 + sub;
    if (row < N_NODES && lane < IN_DIM) sx[sub][lane] = x[row * IN_DIM + lane];
    __syncthreads();
    float acc = sb0[lane];
#pragma unroll
    for (int k = 0; k < IN_DIM; k++) acc += sx[sub][k] * sW0[k * DIM + lane];
    acc = fmaxf(acc, 0.f);
    sh0[sub][lane] = acc;
    __syncthreads();
    float o = 0.f;
#pragma unroll
    for (int k = 0; k < DIM; k++) o += sh0[sub][k] * sWc[k * DIM + lane];
    if (row < N_NODES) hw[row * DIM + lane] = o;
    __syncthreads();
  }
}

// ---------------- zero: cnt (ints) + lstm state (floats) ----------------
__global__ void k_zero2(float* a, int na, int* b, int nb) {
  int i = blockIdx.x * blockDim.x + threadIdx.x;
  if (i < na) a[i] = 0.f;
  else if (i - na < nb) b[i - na] = 0;
}

// ---------------- CSR build: count incoming edges per node ----------------
__global__ void k_count(const int* __restrict__ ei, int* __restrict__ cnt) {
  int e = blockIdx.x * blockDim.x + threadIdx.x;
  if (e < N_EDGES) atomicAdd(&cnt[ei[N_EDGES + e]], 1);
}

// ---------------- CSR build: single-block exclusive scan ----------------
// In-place: cnt[i] (count) -> cnt[i] (exclusive offset, used as fill cursor).
// Also emits dinv[i] = rsqrt(count+1)  (+1 = self loop).
__global__ __launch_bounds__(1024) void k_scan(int* __restrict__ cnt,
                                               float* __restrict__ dinv) {
  __shared__ int wsums[16];
  __shared__ int carry;
  int t = threadIdx.x, lane = t & 63, w = t >> 6;
  if (t == 0) carry = 0;
  __syncthreads();
  for (int base = 0; base < N_NODES; base += 8192) {
    int i0 = base + t * 8;
    int v[8];
    int local = 0;
#pragma unroll
    for (int k = 0; k < 8; k++) {
      int i = i0 + k;
      v[k] = (i < N_NODES) ? cnt[i] : 0;
      local += v[k];
    }
    int x = local;
#pragma unroll
    for (int d = 1; d < 64; d <<= 1) {
      int y = __shfl_up(x, d, 64);
      if (lane >= d) x += y;
    }
    if (lane == 63) wsums[w] = x;
    __syncthreads();
    if (t < 16) {
      int y = wsums[t];
#pragma unroll
      for (int d = 1; d < 16; d <<= 1) {
        int z = __shfl_up(y, d, 64);
        if (t >= d) y += z;
      }
      wsums[t] = y;
    }
    __syncthreads();
    int excl = x - local + ((w > 0) ? wsums[w - 1] : 0) + carry;
#pragma unroll
    for (int k = 0; k < 8; k++) {
      int i = i0 + k;
      if (i < N_NODES) {
        cnt[i] = excl;  // cursor = exclusive offset
        dinv[i] = rsqrtf((float)(v[k] + 1));
        excl += v[k];
      }
    }
    __syncthreads();
    if (t == 0) carry += wsums[15];
    __syncthreads();
  }
}

// ---------------- CSR build: fill adjacency (by destination) ----------------
__global__ void k_fill(const int* __restrict__ ei, int* __restrict__ cursor,
                       int* __restrict__ adj) {
  int e = blockIdx.x * blockDim.x + threadIdx.x;
  if (e < N_EDGES) {
    int row = ei[e];
    int col = ei[N_EDGES + e];
    int slot = atomicAdd(&cursor[col], 1);
    adj[slot] = row;
  }
}

// ---------------- GCN aggregate: gather per node (one wave per node) ------
// After k_fill, cursor[i] == inclusive end offset of node i's segment.
// Fuses self-loop, dinv normalization, +bc, relu.
__global__ __launch_bounds__(256) void k_gather(const int* __restrict__ adj,
    const int* __restrict__ cursor, const float* __restrict__ hw,
    const float* __restrict__ dinv, const float* __restrict__ bc,
    float* __restrict__ h) {
  int node = blockIdx.x * 4 + (threadIdx.x >> 6);
  int lane = threadIdx.x & 63;
  if (node >= N_NODES) return;
  int eend = cursor[node];
  int s = (node == 0) ? 0 : cursor[node - 1];
  float di = dinv[node];
  float acc = di * hw[node * DIM + lane];  // self loop (norm di*di, one di applied at end)
  for (int cb = s; cb < eend; cb += 64) {
    int cn = min(64, eend - cb);
    int idx = (lane < cn) ? adj[cb + lane] : 0;
    float dv = (lane < cn) ? dinv[idx] : 0.f;
    for (int j = 0; j < cn; j++) {
      int r = __shfl(idx, j, 64);
      float dr = __shfl(dv, j, 64);
      acc += dr * hw[r * DIM + lane];
    }
  }
  h[node * DIM + lane] = fmaxf(acc * di + bc[lane], 0.f);
}

// ---------------- graph boundaries (batch is sorted) ----------------
__global__ void k_starts(const int* __restrict__ batch, int* __restrict__ start) {
  int g = blockIdx.x * blockDim.x + threadIdx.x;
  if (g > NGRAPH) return;
  if (g == NGRAPH) { start[NGRAPH] = N_NODES; return; }
  int lo = 0, hi = N_NODES;
  while (lo < hi) {
    int mid = (lo + hi) >> 1;
    if (batch[mid] < g) lo = mid + 1; else hi = mid;
  }
  start[g] = lo;
}

// ---------------- LSTM cell (one block per graph) ----------------
__global__ __launch_bounds__(256) void k_lstm(const float* __restrict__ Wih,
    const float* __restrict__ Whh, const float* __restrict__ bih,
    const float* __restrict__ bhh, float* __restrict__ hs, float* __restrict__ cs,
    float* __restrict__ q_star) {
  int b = blockIdx.x, t = threadIdx.x;
  __shared__ float sq[2 * DIM];
  __shared__ float shh[DIM];
  __shared__ float gates[4 * DIM];
  if (t < 2 * DIM) sq[t] = q_star[b * 2 * DIM + t];
  else if (t < 3 * DIM) shh[t - 2 * DIM] = hs[b * DIM + (t - 2 * DIM)];
  __syncthreads();
  float g = bih[t] + bhh[t];
  const float* wr = Wih + t * 2 * DIM;
#pragma unroll 8
  for (int k = 0; k < 2 * DIM; k++) g += sq[k] * wr[k];
  const float* wh = Whh + t * DIM;
#pragma unroll 8
  for (int k = 0; k < DIM; k++) g += shh[k] * wh[k];
  gates[t] = g;
  __syncthreads();
  if (t < DIM) {
    float ig = sigmoidf(gates[t]);
    float fg = sigmoidf(gates[DIM + t]);
    float gg = tanhf(gates[2 * DIM + t]);
    float og = sigmoidf(gates[3 * DIM + t]);
    float c = fg * cs[b * DIM + t] + ig * gg;
    cs[b * DIM + t] = c;
    float hh = og * tanhf(c);
    hs[b * DIM + t] = hh;
    q_star[b * 2 * DIM + t] = hh;  // q half of q_star
  }
}

// ---------------- segment softmax attention (one block per graph) ----------------
#define MAXC 128
__global__ __launch_bounds__(256) void k_attn(const float* __restrict__ h,
    const float* __restrict__ hs, const int* __restrict__ start,
    float* __restrict__ q_star) {
  int b = blockIdx.x, t = threadIdx.x;
  int wave = t >> 6, lane = t & 63;
  __shared__ float sq[DIM];
  __shared__ float e_s[MAXC];
  __shared__ float red[4 * DIM];
  __shared__ float lred[4];
  int s = start[b], eend = start[b + 1];
  if (t < DIM) sq[t] = hs[b * DIM + t];
  __syncthreads();
  float m_run = -INFINITY, l_run = 0.f, racc = 0.f;
  for (int cb = s; cb < eend; cb += MAXC) {
    int cn = min(MAXC, eend - cb);
    for (int j = wave; j < cn; j += 4) {
      float p = h[(cb + j) * DIM + lane] * sq[lane];
      p = wsum(p);
      if (lane == 0) e_s[j] = p;
    }
    __syncthreads();
    float m_c = -INFINITY;
    for (int j = 0; j < cn; j++) m_c = fmaxf(m_c, e_s[j]);
    float m_new = fmaxf(m_run, m_c);
    float scale = expf(m_run - m_new);
    racc *= scale;
    l_run *= scale;
    m_run = m_new;
    for (int j = wave; j < cn; j += 4) {
      float a = expf(e_s[j] - m_run);
      l_run += a;
      racc += a * h[(cb + j) * DIM + lane];
    }
    __syncthreads();
  }
  red[wave * DIM + lane] = racc;
  if (lane == 0) lred[wave] = l_run;
  __syncthreads();
  if (t < DIM) {
    float r = red[t] + red[DIM + t] + red[2 * DIM + t] + red[3 * DIM + t];
    float l = lred[0] + lred[1] + lred[2] + lred[3];
    r = (l > 0.f) ? r / l : 0.f;
    q_star[b * 2 * DIM + DIM + t] = r;
  }
}

// ---------------- output MLP (one wave per graph) ----------------
__global__ __launch_bounds__(64) void k_final(const float* __restrict__ q_star,
    const float* __restrict__ W1, const float* __restrict__ b1,
    const float* __restrict__ W2, const float* __restrict__ b2,
    float* __restrict__ out) {
  int b = blockIdx.x, t = threadIdx.x;
  __shared__ float sq[2 * DIM];
  sq[t] = q_star[b * 2 * DIM + t];
  sq[t + DIM] = q_star[b * 2 * DIM + DIM + t];
  __syncthreads();
  float acc = b1[t];
#pragma unroll 8
  for (int k = 0; k < 2 * DIM; k++) acc += sq[k] * W1[k * DIM + t];
  acc = fmaxf(acc, 0.f);
  float v = wsum(acc * W2[t]);
  if (t == 0) out[b] = v + b2[0];
}

extern "C" void kernel_launch(void* const* d_in, const int* in_sizes, int n_in,
                              void* d_out, int out_size, void* d_ws, size_t ws_size,
                              hipStream_t stream) {
  const float* x    = (const float*)d_in[0];
  const int*   ei   = (const int*)d_in[1];
  const int*   batch= (const int*)d_in[2];
  const float* W0   = (const float*)d_in[3];
  const float* b0   = (const float*)d_in[4];
  const float* Wc   = (const float*)d_in[5];
  const float* bc   = (const float*)d_in[6];
  const float* Wih  = (const float*)d_in[7];
  const float* Whh  = (const float*)d_in[8];
  const float* bih  = (const float*)d_in[9];
  const float* bhh  = (const float*)d_in[10];
  const float* W1   = (const float*)d_in[11];
  const float* b1   = (const float*)d_in[12];
  const float* W2   = (const float*)d_in[13];
  const float* b2   = (const float*)d_in[14];
  float* out = (float*)d_out;

  float* ws   = (float*)d_ws;
  float* hw   = ws;                              // N*DIM
  float* h    = hw + (size_t)N_NODES * DIM;      // N*DIM
  float* dinv = h + (size_t)N_NODES * DIM;       // N
  float* hs   = dinv + N_NODES;                  // NGRAPH*DIM
  float* cs   = hs + NGRAPH * DIM;               // NGRAPH*DIM
  float* qst  = cs + NGRAPH * DIM;               // NGRAPH*2*DIM
  int* cnt    = (int*)(qst + NGRAPH * 2 * DIM);  // N (count -> cursor -> end-offsets)
  int* adj    = cnt + N_NODES;                   // N_EDGES
  int* start  = adj + N_EDGES;                   // NGRAPH+1

  const int nz = NGRAPH * 4 * DIM;  // hs+cs+qst floats
  k_lin0<<<(N_NODES + 63) / 64, 256, 0, stream>>>(x, W0, b0, Wc, hw);
  k_zero2<<<(nz + N_NODES + 255) / 256, 256, 0, stream>>>(hs, nz, cnt, N_NODES);
  k_count<<<(N_EDGES + 255) / 256, 256, 0, stream>>>(ei, cnt);
  k_scan<<<1, 1024, 0, stream>>>(cnt, dinv);
  k_fill<<<(N_EDGES + 255) / 256, 256, 0, stream>>>(ei, cnt, adj);
  k_gather<<<(N_NODES + 3) / 4, 256, 0, stream>>>(adj, cnt, hw, dinv, bc, h);
  k_starts<<<(NGRAPH + 256) / 256, 256, 0, stream>>>(batch, start);
  for (int s = 0; s < 3; s++) {
    k_lstm<<<NGRAPH, 256, 0, stream>>>(Wih, Whh, bih, bhh, hs, cs, qst);
    k_attn<<<NGRAPH, 256, 0, stream>>>(h, hs, start, qst);
  }
  k_final<<<NGRAPH, 64, 0, stream>>>(qst, W1, b1, W2, b2, out);
}

// Round 3
// 376.659 us; speedup vs baseline: 1.3652x; 1.1058x over previous
//
#include <hip/hip_runtime.h>
#include <math.h>

#define N_NODES 50000
#define N_EDGES 800000
#define NGRAPH  1024
#define IN_DIM  25
#define DIM     64

__device__ inline float wsum(float v) {
#pragma unroll
  for (int off = 32; off > 0; off >>= 1) v += __shfl_xor(v, off, 64);
  return v;
}
__device__ inline float sigmoidf(float x) { return 1.f / (1.f + expf(-x)); }

// ---------------- lin0 + relu + @Wc fused ----------------
__global__ __launch_bounds__(256) void k_lin0(const float* __restrict__ x,
    const float* __restrict__ W0, const float* __restrict__ b0,
    const float* __restrict__ Wc, float* __restrict__ hw) {
  __shared__ float sW0[IN_DIM * DIM];
  __shared__ float sWc[DIM * DIM];
  __shared__ float sb0[DIM];
  __shared__ float sx[4][IN_DIM];
  __shared__ float sh0[4][DIM];
  int t = threadIdx.x;
  for (int i = t; i < IN_DIM * DIM; i += 256) sW0[i] = W0[i];
  for (int i = t; i < DIM * DIM; i += 256) sWc[i] = Wc[i];
  if (t < DIM) sb0[t] = b0[t];
  __syncthreads();
  int sub = t >> 6, lane = t & 63;
  const int ITER = 16;
  int base = blockIdx.x * (4 * ITER);
  for (int r = 0; r < ITER; r++) {
    int row = base + r * 4 + sub;
    if (row < N_NODES && lane < IN_DIM) sx[sub][lane] = x[row * IN_DIM + lane];
    __syncthreads();
    float acc = sb0[lane];
#pragma unroll
    for (int k = 0; k < IN_DIM; k++) acc += sx[sub][k] * sW0[k * DIM + lane];
    acc = fmaxf(acc, 0.f);
    sh0[sub][lane] = acc;
    __syncthreads();
    float o = 0.f;
#pragma unroll
    for (int k = 0; k < DIM; k++) o += sh0[sub][k] * sWc[k * DIM + lane];
    if (row < N_NODES) hw[row * DIM + lane] = o;
    __syncthreads();
  }
}

// ---------------- CSR build: count incoming edges per node ----------------
__global__ void k_count(const int* __restrict__ ei, int* __restrict__ cnt) {
  int e = blockIdx.x * blockDim.x + threadIdx.x;
  if (e < N_EDGES) atomicAdd(&cnt[ei[N_EDGES + e]], 1);
}

// ---------------- CSR build: single-block exclusive scan ----------------
// In-place: cnt[i] (count) -> cnt[i] (exclusive offset, used as fill cursor).
// Also emits dinv[i] = rsqrt(count+1)  (+1 = self loop).
__global__ __launch_bounds__(1024) void k_scan(int* __restrict__ cnt,
                                               float* __restrict__ dinv) {
  __shared__ int wsums[16];
  __shared__ int carry;
  int t = threadIdx.x, lane = t & 63, w = t >> 6;
  if (t == 0) carry = 0;
  __syncthreads();
  for (int base = 0; base < N_NODES; base += 8192) {
    int i0 = base + t * 8;
    int v[8];
    int local = 0;
#pragma unroll
    for (int k = 0; k < 8; k++) {
      int i = i0 + k;
      v[k] = (i < N_NODES) ? cnt[i] : 0;
      local += v[k];
    }
    int x = local;
#pragma unroll
    for (int d = 1; d < 64; d <<= 1) {
      int y = __shfl_up(x, d, 64);
      if (lane >= d) x += y;
    }
    if (lane == 63) wsums[w] = x;
    __syncthreads();
    if (t < 16) {
      int y = wsums[t];
#pragma unroll
      for (int d = 1; d < 16; d <<= 1) {
        int z = __shfl_up(y, d, 64);
        if (t >= d) y += z;
      }
      wsums[t] = y;
    }
    __syncthreads();
    int excl = x - local + ((w > 0) ? wsums[w - 1] : 0) + carry;
#pragma unroll
    for (int k = 0; k < 8; k++) {
      int i = i0 + k;
      if (i < N_NODES) {
        cnt[i] = excl;  // cursor = exclusive offset
        dinv[i] = rsqrtf((float)(v[k] + 1));
        excl += v[k];
      }
    }
    __syncthreads();
    if (t == 0) carry += wsums[15];
    __syncthreads();
  }
}

// ---------------- CSR build: fill adjacency (by destination) ----------------
__global__ void k_fill(const int* __restrict__ ei, int* __restrict__ cursor,
                       int* __restrict__ adj) {
  int e = blockIdx.x * blockDim.x + threadIdx.x;
  if (e < N_EDGES) {
    int row = ei[e];
    int col = ei[N_EDGES + e];
    int slot = atomicAdd(&cursor[col], 1);
    adj[slot] = row;
  }
}

// ---------------- GCN aggregate: gather per node (one wave per node) ------
// After k_fill, cursor[i] == inclusive end offset of node i's segment.
// Fuses self-loop, dinv normalization, +bc, relu.
__global__ __launch_bounds__(256) void k_gather(const int* __restrict__ adj,
    const int* __restrict__ cursor, const float* __restrict__ hw,
    const float* __restrict__ dinv, const float* __restrict__ bc,
    float* __restrict__ h) {
  int node = blockIdx.x * 4 + (threadIdx.x >> 6);
  int lane = threadIdx.x & 63;
  if (node >= N_NODES) return;
  int eend = cursor[node];
  int s = (node == 0) ? 0 : cursor[node - 1];
  float di = dinv[node];
  float acc = di * hw[node * DIM + lane];  // self loop (one di applied at end)
  for (int cb = s; cb < eend; cb += 64) {
    int cn = min(64, eend - cb);
    int idx = (lane < cn) ? adj[cb + lane] : 0;
    float dv = (lane < cn) ? dinv[idx] : 0.f;
    for (int j = 0; j < cn; j++) {
      int r = __shfl(idx, j, 64);
      float dr = __shfl(dv, j, 64);
      acc += dr * hw[r * DIM + lane];
    }
  }
  h[node * DIM + lane] = fmaxf(acc * di + bc[lane], 0.f);
}

// ---------------- fused Set2Set: 3x(LSTM + segment-softmax) + MLP head ----
// One block per graph. All state in LDS; weights from L2.
__global__ __launch_bounds__(256) void k_set2set(
    const float* __restrict__ h, const int* __restrict__ batch,
    const float* __restrict__ Wih, const float* __restrict__ Whh,
    const float* __restrict__ bih, const float* __restrict__ bhh,
    const float* __restrict__ W1, const float* __restrict__ b1,
    const float* __restrict__ W2, const float* __restrict__ b2,
    float* __restrict__ out) {
  int b = blockIdx.x, t = threadIdx.x;
  int wave = t >> 6, lane = t & 63;
  __shared__ float qs[2 * DIM];       // q_star
  __shared__ float hsl[DIM], csl[DIM];
  __shared__ float gates[4 * DIM];
  __shared__ float e_s[256];
  __shared__ float red[4 * DIM];
  __shared__ float lred[4], wmax[4];
  __shared__ int seg[2];
  if (t < 2) {  // graph boundary via binary search on sorted batch
    int g = b + t;
    int lo = 0, hi = N_NODES;
    if (g == NGRAPH) lo = N_NODES;
    else while (lo < hi) { int mid = (lo + hi) >> 1; if (batch[mid] < g) lo = mid + 1; else hi = mid; }
    seg[t] = lo;
  }
  if (t < 2 * DIM) qs[t] = 0.f;
  if (t < DIM) { hsl[t] = 0.f; csl[t] = 0.f; }
  __syncthreads();
  int s = seg[0], eend = seg[1];
  for (int step = 0; step < 3; step++) {
    // ---- LSTM cell: thread t computes gate t ----
    float g = bih[t] + bhh[t];
    const float4* wr = (const float4*)(Wih + t * 2 * DIM);
#pragma unroll
    for (int k = 0; k < 2 * DIM / 4; k++) {
      float4 w4 = wr[k];
      g += qs[4 * k] * w4.x + qs[4 * k + 1] * w4.y + qs[4 * k + 2] * w4.z + qs[4 * k + 3] * w4.w;
    }
    const float4* wh = (const float4*)(Whh + t * DIM);
#pragma unroll
    for (int k = 0; k < DIM / 4; k++) {
      float4 w4 = wh[k];
      g += hsl[4 * k] * w4.x + hsl[4 * k + 1] * w4.y + hsl[4 * k + 2] * w4.z + hsl[4 * k + 3] * w4.w;
    }
    gates[t] = g;
    __syncthreads();
    if (t < DIM) {
      float ig = sigmoidf(gates[t]);
      float fg = sigmoidf(gates[DIM + t]);
      float gg = tanhf(gates[2 * DIM + t]);
      float og = sigmoidf(gates[3 * DIM + t]);
      float c = fg * csl[t] + ig * gg;
      csl[t] = c;
      float hh = og * tanhf(c);
      hsl[t] = hh;
      qs[t] = hh;  // q half of q_star
    }
    __syncthreads();
    // ---- segment softmax attention (online, chunked) ----
    float m_run = -INFINITY, l_w = 0.f, racc = 0.f;
    for (int cb = s; cb < eend; cb += 256) {
      int cn = min(256, eend - cb);
      for (int j = wave; j < cn; j += 4) {
        float p = h[(size_t)(cb + j) * DIM + lane] * hsl[lane];
        p = wsum(p);
        if (lane == 0) e_s[j] = p;
      }
      __syncthreads();
      float mv = (t < cn) ? e_s[t] : -INFINITY;
#pragma unroll
      for (int off = 32; off > 0; off >>= 1) mv = fmaxf(mv, __shfl_xor(mv, off, 64));
      if (lane == 0) wmax[wave] = mv;
      __syncthreads();
      float m_c = fmaxf(fmaxf(wmax[0], wmax[1]), fmaxf(wmax[2], wmax[3]));
      float m_new = fmaxf(m_run, m_c);
      float scale = expf(m_run - m_new);  // first chunk: racc=l_w=0 anyway
      racc *= scale;
      l_w *= scale;
      m_run = m_new;
      for (int j = wave; j < cn; j += 4) {
        float a = expf(e_s[j] - m_run);
        l_w += a;  // lane-uniform within wave
        racc += a * h[(size_t)(cb + j) * DIM + lane];
      }
      __syncthreads();
    }
    red[wave * DIM + lane] = racc;
    if (lane == 0) lred[wave] = l_w;
    __syncthreads();
    if (t < DIM) {
      float r = red[t] + red[DIM + t] + red[2 * DIM + t] + red[3 * DIM + t];
      float l = lred[0] + lred[1] + lred[2] + lred[3];
      qs[DIM + t] = (l > 0.f) ? r / l : 0.f;
    }
    __syncthreads();
  }
  // ---- output MLP head ----
  if (t < DIM) {
    float acc = b1[t];
#pragma unroll
    for (int k = 0; k < 2 * DIM; k++) acc += qs[k] * W1[k * DIM + t];
    acc = fmaxf(acc, 0.f);
    float v = wsum(acc * W2[t]);
    if (t == 0) out[b] = v + b2[0];
  }
}

extern "C" void kernel_launch(void* const* d_in, const int* in_sizes, int n_in,
                              void* d_out, int out_size, void* d_ws, size_t ws_size,
                              hipStream_t stream) {
  const float* x    = (const float*)d_in[0];
  const int*   ei   = (const int*)d_in[1];
  const int*   batch= (const int*)d_in[2];
  const float* W0   = (const float*)d_in[3];
  const float* b0   = (const float*)d_in[4];
  const float* Wc   = (const float*)d_in[5];
  const float* bc   = (const float*)d_in[6];
  const float* Wih  = (const float*)d_in[7];
  const float* Whh  = (const float*)d_in[8];
  const float* bih  = (const float*)d_in[9];
  const float* bhh  = (const float*)d_in[10];
  const float* W1   = (const float*)d_in[11];
  const float* b1   = (const float*)d_in[12];
  const float* W2   = (const float*)d_in[13];
  const float* b2   = (const float*)d_in[14];
  float* out = (float*)d_out;

  float* ws   = (float*)d_ws;
  float* hw   = ws;                              // N*DIM
  float* h    = hw + (size_t)N_NODES * DIM;      // N*DIM
  float* dinv = h + (size_t)N_NODES * DIM;       // N
  int* cnt    = (int*)(dinv + N_NODES);          // N (count -> cursor -> end-offsets)
  int* adj    = cnt + N_NODES;                   // N_EDGES

  k_lin0<<<(N_NODES + 63) / 64, 256, 0, stream>>>(x, W0, b0, Wc, hw);
  hipMemsetAsync(cnt, 0, N_NODES * sizeof(int), stream);
  k_count<<<(N_EDGES + 255) / 256, 256, 0, stream>>>(ei, cnt);
  k_scan<<<1, 1024, 0, stream>>>(cnt, dinv);
  k_fill<<<(N_EDGES + 255) / 256, 256, 0, stream>>>(ei, cnt, adj);
  k_gather<<<(N_NODES + 3) / 4, 256, 0, stream>>>(adj, cnt, hw, dinv, bc, h);
  k_set2set<<<NGRAPH, 256, 0, stream>>>(h, batch, Wih, Whh, bih, bhh, W1, b1, W2, b2, out);
}

// Round 4
// 357.188 us; speedup vs baseline: 1.4396x; 1.0545x over previous
//
#include <hip/hip_runtime.h>
#include <math.h>

#define N_NODES 50000
#define N_EDGES 800000
#define NGRAPH  1024
#define IN_DIM  25
#define DIM     64

__device__ inline float wsum(float v) {
#pragma unroll
  for (int off = 32; off > 0; off >>= 1) v += __shfl_xor(v, off, 64);
  return v;
}
__device__ inline float sigmoidf(float x) { return 1.f / (1.f + expf(-x)); }

// ---------------- lin0 + relu + @Wc fused (wave-independent rows) ----------
__global__ __launch_bounds__(256) void k_lin0(const float* __restrict__ x,
    const float* __restrict__ W0, const float* __restrict__ b0,
    const float* __restrict__ Wc, float* __restrict__ hw) {
  __shared__ float sW0[IN_DIM * DIM];
  __shared__ float sWc[DIM * DIM];
  __shared__ float sb0[DIM];
  int t = threadIdx.x;
  for (int i = t; i < IN_DIM * DIM; i += 256) sW0[i] = W0[i];
  for (int i = t; i < DIM * DIM; i += 256) sWc[i] = Wc[i];
  if (t < DIM) sb0[t] = b0[t];
  __syncthreads();
  int wave = t >> 6, lane = t & 63;
  const int RPW = 16;  // rows per wave
  int row0 = (blockIdx.x * 4 + wave) * RPW;
  for (int r = 0; r < RPW; r++) {
    int row = row0 + r;
    if (row >= N_NODES) return;
    float xv = (lane < IN_DIM) ? x[row * IN_DIM + lane] : 0.f;
    float h0 = sb0[lane];
#pragma unroll
    for (int k = 0; k < IN_DIM; k++) h0 += __shfl(xv, k, 64) * sW0[k * DIM + lane];
    h0 = fmaxf(h0, 0.f);
    float o0 = 0.f, o1 = 0.f;
#pragma unroll
    for (int k = 0; k < DIM; k += 2) {
      o0 += __shfl(h0, k, 64) * sWc[k * DIM + lane];
      o1 += __shfl(h0, k + 1, 64) * sWc[(k + 1) * DIM + lane];
    }
    hw[row * DIM + lane] = o0 + o1;
  }
}

// ---------------- CSR build: count incoming edges per node ----------------
__global__ void k_count(const int* __restrict__ ei, int* __restrict__ cnt) {
  int e = blockIdx.x * blockDim.x + threadIdx.x;
  if (e < N_EDGES) atomicAdd(&cnt[ei[N_EDGES + e]], 1);
}

// ---------------- CSR build: single-block exclusive scan ----------------
__global__ __launch_bounds__(1024) void k_scan(int* __restrict__ cnt,
                                               float* __restrict__ dinv) {
  __shared__ int wsums[16];
  __shared__ int carry;
  int t = threadIdx.x, lane = t & 63, w = t >> 6;
  if (t == 0) carry = 0;
  __syncthreads();
  for (int base = 0; base < N_NODES; base += 8192) {
    int i0 = base + t * 8;
    int v[8];
    int local = 0;
#pragma unroll
    for (int k = 0; k < 8; k++) {
      int i = i0 + k;
      v[k] = (i < N_NODES) ? cnt[i] : 0;
      local += v[k];
    }
    int x = local;
#pragma unroll
    for (int d = 1; d < 64; d <<= 1) {
      int y = __shfl_up(x, d, 64);
      if (lane >= d) x += y;
    }
    if (lane == 63) wsums[w] = x;
    __syncthreads();
    if (t < 16) {
      int y = wsums[t];
#pragma unroll
      for (int d = 1; d < 16; d <<= 1) {
        int z = __shfl_up(y, d, 64);
        if (t >= d) y += z;
      }
      wsums[t] = y;
    }
    __syncthreads();
    int excl = x - local + ((w > 0) ? wsums[w - 1] : 0) + carry;
#pragma unroll
    for (int k = 0; k < 8; k++) {
      int i = i0 + k;
      if (i < N_NODES) {
        cnt[i] = excl;
        dinv[i] = rsqrtf((float)(v[k] + 1));
        excl += v[k];
      }
    }
    __syncthreads();
    if (t == 0) carry += wsums[15];
    __syncthreads();
  }
}

// ---------------- CSR build: fill adjacency (by destination) ----------------
__global__ void k_fill(const int* __restrict__ ei, int* __restrict__ cursor,
                       int* __restrict__ adj) {
  int e = blockIdx.x * blockDim.x + threadIdx.x;
  if (e < N_EDGES) {
    int row = ei[e];
    int col = ei[N_EDGES + e];
    int slot = atomicAdd(&cursor[col], 1);
    adj[slot] = row;
  }
}

// ---------------- weight transpose: WT[k][t], k<128: Wih, else Whh --------
__global__ __launch_bounds__(256) void k_wt(const float* __restrict__ Wih,
    const float* __restrict__ Whh, float* __restrict__ WT) {
  int k = blockIdx.x, t = threadIdx.x;
  float v = (k < 2 * DIM) ? Wih[t * 2 * DIM + k] : Whh[t * DIM + (k - 2 * DIM)];
  WT[k * 4 * DIM + t] = v;
}

// ---------------- GCN aggregate: gather per node (one wave per node) ------
__global__ __launch_bounds__(256) void k_gather(const int* __restrict__ adj,
    const int* __restrict__ cursor, const float* __restrict__ hw,
    const float* __restrict__ dinv, const float* __restrict__ bc,
    float* __restrict__ h) {
  int node = blockIdx.x * 4 + (threadIdx.x >> 6);
  int lane = threadIdx.x & 63;
  if (node >= N_NODES) return;
  int eend = cursor[node];
  int s = (node == 0) ? 0 : cursor[node - 1];
  float di = dinv[node];
  float acc = di * hw[node * DIM + lane];  // self loop (one di applied at end)
  for (int cb = s; cb < eend; cb += 64) {
    int cn = min(64, eend - cb);
    int idx = (lane < cn) ? adj[cb + lane] : 0;
    float dv = (lane < cn) ? dinv[idx] : 0.f;
    float a0 = 0.f, a1 = 0.f, a2 = 0.f, a3 = 0.f;
    int j = 0;
    for (; j + 4 <= cn; j += 4) {
      int r0 = __shfl(idx, j, 64), r1 = __shfl(idx, j + 1, 64);
      int r2 = __shfl(idx, j + 2, 64), r3 = __shfl(idx, j + 3, 64);
      float d0 = __shfl(dv, j, 64), d1 = __shfl(dv, j + 1, 64);
      float d2 = __shfl(dv, j + 2, 64), d3 = __shfl(dv, j + 3, 64);
      a0 += d0 * hw[(size_t)r0 * DIM + lane];
      a1 += d1 * hw[(size_t)r1 * DIM + lane];
      a2 += d2 * hw[(size_t)r2 * DIM + lane];
      a3 += d3 * hw[(size_t)r3 * DIM + lane];
    }
    for (; j < cn; j++) {
      int r = __shfl(idx, j, 64);
      float dr = __shfl(dv, j, 64);
      a0 += dr * hw[(size_t)r * DIM + lane];
    }
    acc += (a0 + a1) + (a2 + a3);
  }
  h[node * DIM + lane] = fmaxf(acc * di + bc[lane], 0.f);
}

// ---------------- fused Set2Set: 3x(LSTM + segment-softmax) + MLP head ----
__global__ __launch_bounds__(256) void k_set2set(
    const float* __restrict__ h, const int* __restrict__ batch,
    const float* __restrict__ WT, const float* __restrict__ bih,
    const float* __restrict__ bhh, const float* __restrict__ W1,
    const float* __restrict__ b1, const float* __restrict__ W2,
    const float* __restrict__ b2, float* __restrict__ out) {
  int b = blockIdx.x, t = threadIdx.x;
  int wave = t >> 6, lane = t & 63;
  __shared__ float qs[2 * DIM];
  __shared__ float hsl[DIM], csl[DIM];
  __shared__ float gates[4 * DIM];
  __shared__ float e_s[256];
  __shared__ float red[4 * DIM];
  __shared__ float lred[4], wmax[4];
  __shared__ int seg[2];
  if (t < 2) {  // graph boundary via binary search on sorted batch
    int g = b + t;
    int lo = 0, hi = N_NODES;
    if (g == NGRAPH) lo = N_NODES;
    else while (lo < hi) { int mid = (lo + hi) >> 1; if (batch[mid] < g) lo = mid + 1; else hi = mid; }
    seg[t] = lo;
  }
  if (t < 2 * DIM) qs[t] = 0.f;
  if (t < DIM) { hsl[t] = 0.f; csl[t] = 0.f; }
  __syncthreads();
  int s = seg[0], eend = seg[1];
  float bsum = bih[t] + bhh[t];
  for (int step = 0; step < 3; step++) {
    // ---- LSTM cell: thread t computes gate t (coalesced WT reads) ----
    float g = bsum;
    if (step > 0) {  // step 0: q_star = hs = 0 -> matmul contributes nothing
      const float* wp = WT + t;
      float g1 = 0.f;
#pragma unroll 8
      for (int k = 0; k < 2 * DIM; k += 2) {
        g += qs[k] * wp[k * 4 * DIM];
        g1 += qs[k + 1] * wp[(k + 1) * 4 * DIM];
      }
#pragma unroll 8
      for (int k = 0; k < DIM; k += 2) {
        g += hsl[k] * wp[(2 * DIM + k) * 4 * DIM];
        g1 += hsl[k + 1] * wp[(2 * DIM + k + 1) * 4 * DIM];
      }
      g += g1;
    }
    gates[t] = g;
    __syncthreads();
    if (t < DIM) {
      float ig = sigmoidf(gates[t]);
      float fg = sigmoidf(gates[DIM + t]);
      float gg = tanhf(gates[2 * DIM + t]);
      float og = sigmoidf(gates[3 * DIM + t]);
      float c = fg * csl[t] + ig * gg;
      csl[t] = c;
      float hh = og * tanhf(c);
      hsl[t] = hh;
      qs[t] = hh;  // q half of q_star
    }
    __syncthreads();
    // ---- segment softmax attention (online, chunked) ----
    float m_run = -INFINITY, l_w = 0.f, racc = 0.f;
    for (int cb = s; cb < eend; cb += 256) {
      int cn = min(256, eend - cb);
      for (int j = wave; j < cn; j += 4) {
        float p = h[(size_t)(cb + j) * DIM + lane] * hsl[lane];
        p = wsum(p);
        if (lane == 0) e_s[j] = p;
      }
      __syncthreads();
      float mv = (t < cn) ? e_s[t] : -INFINITY;
#pragma unroll
      for (int off = 32; off > 0; off >>= 1) mv = fmaxf(mv, __shfl_xor(mv, off, 64));
      if (lane == 0) wmax[wave] = mv;
      __syncthreads();
      float m_c = fmaxf(fmaxf(wmax[0], wmax[1]), fmaxf(wmax[2], wmax[3]));
      float m_new = fmaxf(m_run, m_c);
      float scale = expf(m_run - m_new);
      racc *= scale;
      l_w *= scale;
      m_run = m_new;
      for (int j = wave; j < cn; j += 4) {
        float a = expf(e_s[j] - m_run);
        l_w += a;  // lane-uniform within wave
        racc += a * h[(size_t)(cb + j) * DIM + lane];
      }
      __syncthreads();
    }
    red[wave * DIM + lane] = racc;
    if (lane == 0) lred[wave] = l_w;
    __syncthreads();
    if (t < DIM) {
      float r = red[t] + red[DIM + t] + red[2 * DIM + t] + red[3 * DIM + t];
      float l = lred[0] + lred[1] + lred[2] + lred[3];
      qs[DIM + t] = (l > 0.f) ? r / l : 0.f;
    }
    __syncthreads();
  }
  // ---- output MLP head ----
  if (t < DIM) {
    float acc = b1[t];
#pragma unroll
    for (int k = 0; k < 2 * DIM; k++) acc += qs[k] * W1[k * DIM + t];
    acc = fmaxf(acc, 0.f);
    float v = wsum(acc * W2[t]);
    if (t == 0) out[b] = v + b2[0];
  }
}

extern "C" void kernel_launch(void* const* d_in, const int* in_sizes, int n_in,
                              void* d_out, int out_size, void* d_ws, size_t ws_size,
                              hipStream_t stream) {
  const float* x    = (const float*)d_in[0];
  const int*   ei   = (const int*)d_in[1];
  const int*   batch= (const int*)d_in[2];
  const float* W0   = (const float*)d_in[3];
  const float* b0   = (const float*)d_in[4];
  const float* Wc   = (const float*)d_in[5];
  const float* bc   = (const float*)d_in[6];
  const float* Wih  = (const float*)d_in[7];
  const float* Whh  = (const float*)d_in[8];
  const float* bih  = (const float*)d_in[9];
  const float* bhh  = (const float*)d_in[10];
  const float* W1   = (const float*)d_in[11];
  const float* b1   = (const float*)d_in[12];
  const float* W2   = (const float*)d_in[13];
  const float* b2   = (const float*)d_in[14];
  float* out = (float*)d_out;

  float* ws   = (float*)d_ws;
  float* hw   = ws;                              // N*DIM
  float* h    = hw + (size_t)N_NODES * DIM;      // N*DIM
  float* dinv = h + (size_t)N_NODES * DIM;       // N
  float* WT   = dinv + N_NODES;                  // 192*256
  int* cnt    = (int*)(WT + 3 * DIM * 4 * DIM);  // N (count -> cursor -> end-offsets)
  int* adj    = cnt + N_NODES;                   // N_EDGES

  k_lin0<<<(N_NODES + 63) / 64, 256, 0, stream>>>(x, W0, b0, Wc, hw);
  hipMemsetAsync(cnt, 0, N_NODES * sizeof(int), stream);
  k_count<<<(N_EDGES + 255) / 256, 256, 0, stream>>>(ei, cnt);
  k_scan<<<1, 1024, 0, stream>>>(cnt, dinv);
  k_fill<<<(N_EDGES + 255) / 256, 256, 0, stream>>>(ei, cnt, adj);
  k_wt<<<3 * DIM, 256, 0, stream>>>(Wih, Whh, WT);
  k_gather<<<(N_NODES + 3) / 4, 256, 0, stream>>>(adj, cnt, hw, dinv, bc, h);
  k_set2set<<<NGRAPH, 256, 0, stream>>>(h, batch, WT, bih, bhh, W1, b1, W2, b2, out);
}